// Round 4
// baseline (247.012 us; speedup 1.0000x reference)
//
#include <hip/hip_runtime.h>

#define DEVI __device__ __forceinline__

typedef __attribute__((ext_vector_type(8))) short bf16x8;
typedef __attribute__((ext_vector_type(4))) short bf16x4;
typedef __attribute__((ext_vector_type(4))) float f32x4;

#define MFMA16 __builtin_amdgcn_mfma_f32_16x16x32_bf16

DEVI short f2bs(float f) {  // fp32 -> bf16 bits, round-nearest-even
  union { float f; unsigned u; } v; v.f = f;
  unsigned r = v.u + 0x7fffu + ((v.u >> 16) & 1u);
  return (short)(r >> 16);
}
DEVI float bs2f(short s) {
  union { unsigned u; float f; } v; v.u = ((unsigned)(unsigned short)s) << 16;
  return v.f;
}

DEVI void gload_lds16(const short* g, short* lds) {
  __builtin_amdgcn_global_load_lds(
      (const __attribute__((address_space(1))) unsigned int*)g,
      (__attribute__((address_space(3))) unsigned int*)lds, 16, 0, 0);
}

// stage a [128 rows][32 k] bf16 chunk (8 KB) packed into LDS. 2 instrs/thread.
DEVI void stage_chunk(short* lds, const short* g, int ldg, int tid) {
#pragma unroll
  for (int it = 0; it < 2; ++it) {
    int slot = it * 256 + tid;          // 0..511
    int row  = slot >> 2;               // 4 lanes per 64 B row
    int ko   = (slot & 3) << 3;
    gload_lds16(g + (size_t)row * ldg + ko, lds + slot * 8);
  }
}

// stage a [64 rows][32 k] bf16 chunk (4 KB). 1 instr/thread.
DEVI void stage_chunk64(short* lds, const short* g, int ldg, int tid) {
  int row = tid >> 2, ko = (tid & 3) << 3;
  gload_lds16(g + (size_t)row * ldg + ko, lds + tid * 8);
}

DEVI bf16x8 lds8(const short* p) { return *(const bf16x8*)p; }

DEVI void zero_acc(f32x4 (&a)[4][4]) {
  f32x4 z = {0.f, 0.f, 0.f, 0.f};
#pragma unroll
  for (int i = 0; i < 4; ++i)
#pragma unroll
    for (int j = 0; j < 4; ++j) a[i][j] = z;
}

// ---------------- K0: x -> xt (transpose+cast) and w1/w2/w3 -> w123 bf16 ----------------
__global__ __launch_bounds__(256) void k_prep(const float* __restrict__ x,
                                              const float* __restrict__ w1,
                                              const float* __restrict__ w2,
                                              const float* __restrict__ w3,
                                              short* __restrict__ xt,
                                              short* __restrict__ w123) {
  int tid = threadIdx.x;
  if (blockIdx.y == 4) {   // weight cast: 256 blocks handle 98304 elements
    int lin = blockIdx.z * 64 + blockIdx.x;
    for (int i = lin * 256 + tid; i < 384 * 256; i += 65536) {
      int r = i >> 8;
      const float* w = (r < 128) ? w1 : (r < 256 ? w2 : w3);
      w123[i] = f2bs(w[(size_t)(r & 127) * 256 + (i & 255)]);
    }
    return;
  }
  __shared__ float t[64][65];
  int b = blockIdx.z;
  int c0 = blockIdx.y * 64;
  int p0 = blockIdx.x * 64;
  const float* xb = x + (size_t)b * 256 * 4096;
#pragma unroll
  for (int i = 0; i < 16; ++i) {
    int idx = i * 256 + tid;
    int c = idx >> 6, p = idx & 63;
    t[p][c] = xb[(size_t)(c0 + c) * 4096 + p0 + p];
  }
  __syncthreads();
  short* xtb = xt + ((size_t)b * 4096 + p0) * 256 + c0;
#pragma unroll
  for (int i = 0; i < 16; ++i) {
    int idx = i * 256 + tid;
    int p = idx >> 6, c = idx & 63;
    xtb[(size_t)p * 256 + c] = f2bs(t[p][c]);
  }
}

// ---------------- K1: projections. theta/phi [pix][ch]; g transposed -> gT [ch][pix] ----------------
__global__ __launch_bounds__(256) void k_proj(const short* __restrict__ xt,
                                              const short* __restrict__ w123,
                                              const float* __restrict__ b1,
                                              const float* __restrict__ b2,
                                              const float* __restrict__ b3,
                                              short* __restrict__ theta,
                                              short* __restrict__ phi,
                                              short* __restrict__ gT) {
  __shared__ short aL[128 * 32];
  __shared__ short bL[128 * 32];
  __shared__ short oL[128 * 136];
  int tid = threadIdx.x;
  int m0 = blockIdx.x * 128;   // pixel tile
  int nb = blockIdx.y;         // 0=theta 1=phi 2=g
  int b  = blockIdx.z;
  int lane = tid & 63, wid = tid >> 6;
  int col = lane & 15, quad = lane >> 4;
  int wm = (wid >> 1) * 64, wn = (wid & 1) * 64;
  const short* A = xt + ((size_t)b * 4096 + m0) * 256;
  const short* B = w123 + (size_t)nb * 128 * 256;
  f32x4 acc[4][4];
  zero_acc(acc);
  for (int ks = 0; ks < 8; ++ks) {
    __syncthreads();
    stage_chunk(aL, A + ks * 32, 256, tid);
    stage_chunk(bL, B + ks * 32, 256, tid);
    __syncthreads();
    bf16x8 af[4], bf_[4];
#pragma unroll
    for (int mi = 0; mi < 4; ++mi) af[mi] = lds8(&aL[(wm + mi * 16 + col) * 32 + quad * 8]);
#pragma unroll
    for (int ni = 0; ni < 4; ++ni) bf_[ni] = lds8(&bL[(wn + ni * 16 + col) * 32 + quad * 8]);
#pragma unroll
    for (int mi = 0; mi < 4; ++mi)
#pragma unroll
      for (int ni = 0; ni < 4; ++ni)
        acc[mi][ni] = MFMA16(af[mi], bf_[ni], acc[mi][ni], 0, 0, 0);
  }
  const float* bias = (nb == 0) ? b1 : (nb == 1 ? b2 : b3);
  __syncthreads();
  if (nb < 2) {
#pragma unroll
    for (int mi = 0; mi < 4; ++mi)
#pragma unroll
      for (int ni = 0; ni < 4; ++ni) {
        float bv = bias[wn + ni * 16 + col];
#pragma unroll
        for (int r = 0; r < 4; ++r)
          oL[(wm + mi * 16 + quad * 4 + r) * 136 + wn + ni * 16 + col] = f2bs(acc[mi][ni][r] + bv);
      }
    __syncthreads();
    short* O = ((nb == 0) ? theta : phi) + ((size_t)b * 4096 + m0) * 128;
#pragma unroll
    for (int it = 0; it < 8; ++it) {
      int slot = it * 256 + tid;            // 2048 slots of 8 shorts
      int r = slot >> 4, cp = (slot & 15) * 8;
      *(bf16x8*)(O + (size_t)r * 128 + cp) = lds8(&oL[r * 136 + cp]);
    }
  } else {
    // transposed epilogue: oL[ch][pix]
#pragma unroll
    for (int mi = 0; mi < 4; ++mi)
#pragma unroll
      for (int ni = 0; ni < 4; ++ni) {
        float bv = bias[wn + ni * 16 + col];
#pragma unroll
        for (int r = 0; r < 4; ++r)
          oL[(wn + ni * 16 + col) * 136 + wm + mi * 16 + quad * 4 + r] = f2bs(acc[mi][ni][r] + bv);
      }
    __syncthreads();
    short* O = gT + (size_t)b * 128 * 4096 + m0;
#pragma unroll
    for (int it = 0; it < 8; ++it) {
      int slot = it * 256 + tid;
      int c = slot >> 4, p8 = (slot & 15) * 8;
      *(bf16x8*)(O + (size_t)c * 4096 + p8) = lds8(&oL[c * 136 + p8]);
    }
  }
}

// ---------------- K2: denom. S^T = phi.theta^T; d[b][j] += sum_i exp (atomic) ----------------
__global__ __launch_bounds__(256, 2) void k_denom(const short* __restrict__ theta,
                                                  const short* __restrict__ phi,
                                                  float* __restrict__ dsum) {
  __shared__ short L[16384];   // theta stage 32 KB, then phi dbuf 2 x 16 KB
  int tid = threadIdx.x;
  int ib = blockIdx.x, jc = blockIdx.y, b = blockIdx.z;
  int lane = tid & 63, wid = tid >> 6;
  int col = lane & 15, quad = lane >> 4;
  int wmj = (wid & 1) * 32;    // m = j
  int wni = (wid >> 1) * 64;   // n = i
  const short* TH = theta + ((size_t)b * 4096 + ib * 128) * 128;
  const short* PH = phi + ((size_t)b * 4096 + (size_t)jc * 1024) * 128;
  float* D = dsum + b * 4096 + jc * 1024;
  // theta [128 i][128 k] -> B-fragments in registers
#pragma unroll
  for (int ks = 0; ks < 4; ++ks) stage_chunk(L + ks * 4096, TH + ks * 32, 128, tid);
  __syncthreads();
  bf16x8 bth[4][4];
#pragma unroll
  for (int ks = 0; ks < 4; ++ks)
#pragma unroll
    for (int ni = 0; ni < 4; ++ni)
      bth[ks][ni] = lds8(&L[ks * 4096 + (wni + ni * 16 + col) * 32 + quad * 8]);
  __syncthreads();
  // prologue: stage phi(0)
#pragma unroll
  for (int ks = 0; ks < 4; ++ks) stage_chunk64(L + ks * 2048, PH + ks * 32, 128, tid);
  for (int jt = 0; jt < 16; ++jt) {
    short* phc = L + (jt & 1) * 8192;
    short* phn = L + ((jt & 1) ^ 1) * 8192;
    __syncthreads();
    if (jt < 15) {
      const short* PHn = PH + (size_t)(jt + 1) * 64 * 128;
#pragma unroll
      for (int ks = 0; ks < 4; ++ks) stage_chunk64(phn + ks * 2048, PHn + ks * 32, 128, tid);
    }
    f32x4 s[2][4];
#pragma unroll
    for (int mi = 0; mi < 2; ++mi)
#pragma unroll
      for (int ni = 0; ni < 4; ++ni) s[mi][ni] = (f32x4){0.f, 0.f, 0.f, 0.f};
#pragma unroll
    for (int ks = 0; ks < 4; ++ks) {
      bf16x8 ap[2];
#pragma unroll
      for (int mi = 0; mi < 2; ++mi) ap[mi] = lds8(&phc[ks * 2048 + (wmj + mi * 16 + col) * 32 + quad * 8]);
#pragma unroll
      for (int mi = 0; mi < 2; ++mi)
#pragma unroll
        for (int ni = 0; ni < 4; ++ni)
          s[mi][ni] = MFMA16(ap[mi], bth[ks][ni], s[mi][ni], 0, 0, 0);
    }
    // d[j] += sum over this wave's 64 i's (4 ni x 16 col)
#pragma unroll
    for (int mi = 0; mi < 2; ++mi)
#pragma unroll
      for (int r = 0; r < 4; ++r) {
        float ps = __expf(s[mi][0][r]) + __expf(s[mi][1][r]) +
                   __expf(s[mi][2][r]) + __expf(s[mi][3][r]);
        ps += __shfl_xor(ps, 1, 16);
        ps += __shfl_xor(ps, 2, 16);
        ps += __shfl_xor(ps, 4, 16);
        ps += __shfl_xor(ps, 8, 16);
        if (col == 0) atomicAdd(D + jt * 64 + wmj + mi * 16 + quad * 4 + r, ps);
      }
  }
}

// ---------------- K3: fused S^T recompute + exp/d -> P (b64 writes) + PV ----------------
// LDS (shorts): ph 0..8191, gp0 8192..16383, gp1 16384..24575, pP 24576..33279 ([128][68])
__global__ __launch_bounds__(256, 2) void k_attn(const short* __restrict__ theta,
                                                 const short* __restrict__ phi,
                                                 const short* __restrict__ gT,
                                                 const float* __restrict__ dsum,
                                                 short* __restrict__ ypart) {
  __shared__ short L[33280];   // 66560 B -> 2 blocks/CU
  int tid = threadIdx.x;
  int ib = blockIdx.x, jc = blockIdx.y, b = blockIdx.z;
  int lane = tid & 63, wid = tid >> 6;
  int col = lane & 15, quad = lane >> 4;
  int wmj = (wid & 1) * 32;    // S^T m = j
  int wni = (wid >> 1) * 64;   // S^T n = i
  int wmi = (wid >> 1) * 64;   // PV m = i
  int wnc = (wid & 1) * 64;    // PV n = c
  const short* TH = theta + ((size_t)b * 4096 + ib * 128) * 128;
  const short* PH = phi + ((size_t)b * 4096 + (size_t)jc * 1024) * 128;
  const short* GT = gT + (size_t)b * 128 * 4096 + jc * 1024;
  const float* DS = dsum + b * 4096 + jc * 1024;
  short* ph = L;
  short* gp0 = L + 8192;
  short* gp1 = L + 16384;
  short* pP = L + 24576;       // [128 i][68 j]
  // theta -> B-fragments (staged across ph+gp0 regions, then re-used)
#pragma unroll
  for (int ks = 0; ks < 4; ++ks) stage_chunk(L + ks * 4096, TH + ks * 32, 128, tid);
  __syncthreads();
  bf16x8 bth[4][4];
#pragma unroll
  for (int ks = 0; ks < 4; ++ks)
#pragma unroll
    for (int ni = 0; ni < 4; ++ni)
      bth[ks][ni] = lds8(&L[ks * 4096 + (wni + ni * 16 + col) * 32 + quad * 8]);
  __syncthreads();
  // prologue: phi(0) + gT(0)
#pragma unroll
  for (int ks = 0; ks < 4; ++ks) stage_chunk64(ph + ks * 2048, PH + ks * 32, 128, tid);
#pragma unroll
  for (int s = 0; s < 2; ++s) stage_chunk(gp0 + s * 4096, GT + s * 32, 4096, tid);
  f32x4 accy[4][4];
  zero_acc(accy);
  for (int jt = 0; jt < 16; ++jt) {
    short* gpc = (jt & 1) ? gp1 : gp0;
    short* gpn = (jt & 1) ? gp0 : gp1;
    // denominator operands (global, L2-hot) issued early
    f32x4 dv[2];
#pragma unroll
    for (int mi = 0; mi < 2; ++mi)
      dv[mi] = *(const f32x4*)(DS + jt * 64 + wmj + mi * 16 + quad * 4);
    __syncthreads();   // phi(jt)/gT(jt) staged; prev-iter pP reads done
    // S^T = phi . theta^T  (m=j 64, n=i 128, K=128)
    f32x4 s[2][4];
#pragma unroll
    for (int mi = 0; mi < 2; ++mi)
#pragma unroll
      for (int ni = 0; ni < 4; ++ni) s[mi][ni] = (f32x4){0.f, 0.f, 0.f, 0.f};
#pragma unroll
    for (int ks = 0; ks < 4; ++ks) {
      bf16x8 ap[2];
#pragma unroll
      for (int mi = 0; mi < 2; ++mi) ap[mi] = lds8(&ph[ks * 2048 + (wmj + mi * 16 + col) * 32 + quad * 8]);
#pragma unroll
      for (int mi = 0; mi < 2; ++mi)
#pragma unroll
        for (int ni = 0; ni < 4; ++ni)
          s[mi][ni] = MFMA16(ap[mi], bth[ks][ni], s[mi][ni], 0, 0, 0);
    }
    // P[i][j] = exp(S)/d[j] — contiguous b64 writes
#pragma unroll
    for (int mi = 0; mi < 2; ++mi) {
      int j0 = wmj + mi * 16 + quad * 4;
      f32x4 rc;
#pragma unroll
      for (int r = 0; r < 4; ++r) rc[r] = __builtin_amdgcn_rcpf(dv[mi][r]);
#pragma unroll
      for (int ni = 0; ni < 4; ++ni) {
        int i = wni + ni * 16 + col;
        bf16x4 pv;
#pragma unroll
        for (int r = 0; r < 4; ++r) pv[r] = f2bs(__expf(s[mi][ni][r]) * rc[r]);
        *(bf16x4*)(pP + i * 68 + j0) = pv;
      }
    }
    __syncthreads();   // pP visible; phi reads done
    if (jt < 15) {
      const short* PHn = PH + (size_t)(jt + 1) * 64 * 128;
#pragma unroll
      for (int ks = 0; ks < 4; ++ks) stage_chunk64(ph + ks * 2048, PHn + ks * 32, 128, tid);
      const short* GTn = GT + (jt + 1) * 64;
#pragma unroll
      for (int s2 = 0; s2 < 2; ++s2) stage_chunk(gpn + s2 * 4096, GTn + s2 * 32, 4096, tid);
    }
    // Y[i][c] += P . gT^T  (m=i 128, n=c 128, K=64)
#pragma unroll
    for (int ksj = 0; ksj < 2; ++ksj) {
      bf16x8 ap2[4], bg[4];
#pragma unroll
      for (int mi = 0; mi < 4; ++mi) ap2[mi] = lds8(&pP[(wmi + mi * 16 + col) * 68 + ksj * 32 + quad * 8]);
#pragma unroll
      for (int ni = 0; ni < 4; ++ni) bg[ni] = lds8(&gpc[ksj * 4096 + (wnc + ni * 16 + col) * 32 + quad * 8]);
#pragma unroll
      for (int mi = 0; mi < 4; ++mi)
#pragma unroll
        for (int ni = 0; ni < 4; ++ni)
          accy[mi][ni] = MFMA16(ap2[mi], bg[ni], accy[mi][ni], 0, 0, 0);
    }
  }
  // epilogue: bf16 partial via pP repack (stride 128), coalesced 16 B stores
  short* Yp = ypart + ((size_t)(jc * 4 + b) * 4096 + (size_t)ib * 128) * 128;
#pragma unroll
  for (int half = 0; half < 2; ++half) {
    __syncthreads();
    if ((wid >> 1) == half) {
#pragma unroll
      for (int mi = 0; mi < 4; ++mi)
#pragma unroll
        for (int ni = 0; ni < 4; ++ni)
#pragma unroll
          for (int r = 0; r < 4; ++r)
            pP[(mi * 16 + quad * 4 + r) * 128 + wnc + ni * 16 + col] = f2bs(accy[mi][ni][r]);
    }
    __syncthreads();
#pragma unroll
    for (int it = 0; it < 4; ++it) {
      int slot = it * 256 + tid;        // 1024 slots of 8 shorts over [64][128]
      int r = slot >> 4, c8 = (slot & 15) * 8;
      *(bf16x8*)(Yp + (size_t)(half * 64 + r) * 128 + c8) = lds8(&pP[r * 128 + c8]);
    }
  }
}

// ---------------- K4: out[o][i] = w4 . (sum of 4 bf16 ypart partials) + b4 + x ----------------
__global__ __launch_bounds__(256) void k_out(const short* __restrict__ ypart,
                                             const float* __restrict__ w4,
                                             const float* __restrict__ b4,
                                             const float* __restrict__ x,
                                             float* __restrict__ out) {
  __shared__ short wL[4 * 4096];   // [ksc][o][32c]
  __shared__ short yL[4 * 4096];   // [ksc][i][32c]
  __shared__ float bLs[128];
  int tid = threadIdx.x;
  int ibk = blockIdx.x, ob = blockIdx.y, b = blockIdx.z;
  int o0 = ob * 128, i0 = ibk * 128;
  int lane = tid & 63, wid = tid >> 6;
  int col = lane & 15, quad = lane >> 4;
  int wm = (wid >> 1) * 64, wn = (wid & 1) * 64;
#pragma unroll
  for (int it = 0; it < 16; ++it) {
    int slot = it * 256 + tid;          // 4096 float4 slots over w4 [128][128]
    int r = slot >> 5, c4 = (slot & 31) * 4;
    int ks = c4 >> 5, cr = c4 & 31;
    f32x4 wv = *(const f32x4*)(w4 + (size_t)(o0 + r) * 128 + c4);
    bf16x4 wp;
#pragma unroll
    for (int e = 0; e < 4; ++e) wp[e] = f2bs(wv[e]);
    *(bf16x4*)&wL[ks * 4096 + r * 32 + cr] = wp;
  }
#pragma unroll
  for (int it = 0; it < 8; ++it) {
    int slot = it * 256 + tid;          // 2048 slots of 8 over y [128][128]
    int r = slot >> 4, c8 = (slot & 15) * 8;
    int ks = c8 >> 5, cr = c8 & 31;
    float a8[8];
#pragma unroll
    for (int e = 0; e < 8; ++e) a8[e] = 0.f;
#pragma unroll
    for (int p = 0; p < 4; ++p) {
      bf16x8 v = *(const bf16x8*)(ypart + ((size_t)(p * 4 + b) * 4096 + i0 + r) * 128 + c8);
#pragma unroll
      for (int e = 0; e < 8; ++e) a8[e] += bs2f(v[e]);
    }
    bf16x8 yv;
#pragma unroll
    for (int e = 0; e < 8; ++e) yv[e] = f2bs(a8[e]);
    *(bf16x8*)&yL[ks * 4096 + r * 32 + cr] = yv;
  }
  if (tid < 128) bLs[tid] = b4[o0 + tid];
  __syncthreads();
  f32x4 acc[4][4];
  zero_acc(acc);
#pragma unroll
  for (int ks = 0; ks < 4; ++ks) {
    bf16x8 af[4], bf_[4];
#pragma unroll
    for (int mi = 0; mi < 4; ++mi) af[mi] = lds8(&wL[ks * 4096 + (wm + mi * 16 + col) * 32 + quad * 8]);
#pragma unroll
    for (int ni = 0; ni < 4; ++ni) bf_[ni] = lds8(&yL[ks * 4096 + (wn + ni * 16 + col) * 32 + quad * 8]);
#pragma unroll
    for (int mi = 0; mi < 4; ++mi)
#pragma unroll
      for (int ni = 0; ni < 4; ++ni)
        acc[mi][ni] = MFMA16(af[mi], bf_[ni], acc[mi][ni], 0, 0, 0);
  }
  const float* X = x + ((size_t)b * 256 + o0) * 4096 + i0;
  float* O = out + ((size_t)b * 256 + o0) * 4096 + i0;
#pragma unroll
  for (int mi = 0; mi < 4; ++mi)
#pragma unroll
    for (int ni = 0; ni < 4; ++ni)
#pragma unroll
      for (int r = 0; r < 4; ++r) {
        int o = wm + mi * 16 + quad * 4 + r;
        int i = wn + ni * 16 + col;
        O[(size_t)o * 4096 + i] = acc[mi][ni][r] + X[(size_t)o * 4096 + i] + bLs[o];
      }
}

extern "C" void kernel_launch(void* const* d_in, const int* in_sizes, int n_in,
                              void* d_out, int out_size, void* d_ws, size_t ws_size,
                              hipStream_t stream) {
  const float* x  = (const float*)d_in[0];
  const float* w1 = (const float*)d_in[1];
  const float* b1 = (const float*)d_in[2];
  const float* w2 = (const float*)d_in[3];
  const float* b2 = (const float*)d_in[4];
  const float* w3 = (const float*)d_in[5];
  const float* b3 = (const float*)d_in[6];
  const float* w4 = (const float*)d_in[7];
  const float* b4 = (const float*)d_in[8];
  char* ws = (char*)d_ws;
  short* xt    = (short*)(ws + 0);          // 8,388,608
  short* w123  = (short*)(ws + 8388608);    //   196,608
  short* theta = (short*)(ws + 8585216);    // 4,194,304
  short* phi   = (short*)(ws + 12779520);   // 4,194,304
  short* gT    = (short*)(ws + 16973824);   // 4,194,304
  float* dsum  = (float*)(ws + 21168128);   //    65,536
  short* ypart = (short*)(ws + 21233664);   // 16,777,216 (end 38,010,880)
  float* out   = (float*)d_out;
  (void)in_sizes; (void)n_in; (void)out_size; (void)ws_size;

  hipMemsetAsync(dsum, 0, 4 * 4096 * sizeof(float), stream);
  k_prep<<<dim3(64, 5, 4), dim3(256), 0, stream>>>(x, w1, w2, w3, xt, w123);
  k_proj<<<dim3(32, 3, 4), dim3(256), 0, stream>>>(xt, w123, b1, b2, b3, theta, phi, gT);
  k_denom<<<dim3(32, 4, 4), dim3(256), 0, stream>>>(theta, phi, dsum);
  k_attn<<<dim3(32, 4, 4), dim3(256), 0, stream>>>(theta, phi, gT, dsum, ypart);
  k_out<<<dim3(32, 2, 4), dim3(256), 0, stream>>>(ypart, w4, b4, x, out);
}

// Round 5
// 202.092 us; speedup vs baseline: 1.2223x; 1.2223x over previous
//
#include <hip/hip_runtime.h>

#define DEVI __device__ __forceinline__

typedef __attribute__((ext_vector_type(8))) short bf16x8;
typedef __attribute__((ext_vector_type(4))) short bf16x4;
typedef __attribute__((ext_vector_type(4))) float f32x4;

#define MFMA16 __builtin_amdgcn_mfma_f32_16x16x32_bf16

DEVI short f2bs(float f) {  // fp32 -> bf16 bits, round-nearest-even
  union { float f; unsigned u; } v; v.f = f;
  unsigned r = v.u + 0x7fffu + ((v.u >> 16) & 1u);
  return (short)(r >> 16);
}
DEVI float bs2f(short s) {
  union { unsigned u; float f; } v; v.u = ((unsigned)(unsigned short)s) << 16;
  return v.f;
}

DEVI void gload_lds16(const short* g, short* lds) {
  __builtin_amdgcn_global_load_lds(
      (const __attribute__((address_space(1))) unsigned int*)g,
      (__attribute__((address_space(3))) unsigned int*)lds, 16, 0, 0);
}

// stage a [128 rows][32 k] bf16 chunk (8 KB) packed into LDS. 2 instrs/thread.
DEVI void stage_chunk(short* lds, const short* g, int ldg, int tid) {
#pragma unroll
  for (int it = 0; it < 2; ++it) {
    int slot = it * 256 + tid;          // 0..511
    int row  = slot >> 2;               // 4 lanes per 64 B row
    int ko   = (slot & 3) << 3;
    gload_lds16(g + (size_t)row * ldg + ko, lds + slot * 8);
  }
}

// stage a [64 rows][32 k] bf16 chunk (4 KB). 1 instr/thread.
DEVI void stage_chunk64(short* lds, const short* g, int ldg, int tid) {
  int row = tid >> 2, ko = (tid & 3) << 3;
  gload_lds16(g + (size_t)row * ldg + ko, lds + tid * 8);
}

DEVI bf16x8 lds8(const short* p) { return *(const bf16x8*)p; }

DEVI void zero_acc(f32x4 (&a)[4][4]) {
  f32x4 z = {0.f, 0.f, 0.f, 0.f};
#pragma unroll
  for (int i = 0; i < 4; ++i)
#pragma unroll
    for (int j = 0; j < 4; ++j) a[i][j] = z;
}

// ---------------- K0: x -> xt (transpose+cast) and w1/w2/w3 -> w123 bf16 ----------------
__global__ __launch_bounds__(256) void k_prep(const float* __restrict__ x,
                                              const float* __restrict__ w1,
                                              const float* __restrict__ w2,
                                              const float* __restrict__ w3,
                                              short* __restrict__ xt,
                                              short* __restrict__ w123) {
  int tid = threadIdx.x;
  if (blockIdx.y == 4) {   // weight cast
    int lin = blockIdx.z * 64 + blockIdx.x;
    for (int i = lin * 256 + tid; i < 384 * 256; i += 65536) {
      int r = i >> 8;
      const float* w = (r < 128) ? w1 : (r < 256 ? w2 : w3);
      w123[i] = f2bs(w[(size_t)(r & 127) * 256 + (i & 255)]);
    }
    return;
  }
  __shared__ float t[64][65];
  int b = blockIdx.z;
  int c0 = blockIdx.y * 64;
  int p0 = blockIdx.x * 64;
  const float* xb = x + (size_t)b * 256 * 4096;
#pragma unroll
  for (int i = 0; i < 16; ++i) {
    int idx = i * 256 + tid;
    int c = idx >> 6, p = idx & 63;
    t[p][c] = xb[(size_t)(c0 + c) * 4096 + p0 + p];
  }
  __syncthreads();
  short* xtb = xt + ((size_t)b * 4096 + p0) * 256 + c0;
#pragma unroll
  for (int i = 0; i < 16; ++i) {
    int idx = i * 256 + tid;
    int p = idx >> 6, c = idx & 63;
    xtb[(size_t)p * 256 + c] = f2bs(t[p][c]);
  }
}

// ---------------- K1: projections (dbuf). theta/phi [pix][ch]; g -> gT [ch][pix] ----------------
__global__ __launch_bounds__(256) void k_proj(const short* __restrict__ xt,
                                              const short* __restrict__ w123,
                                              const float* __restrict__ b1,
                                              const float* __restrict__ b2,
                                              const float* __restrict__ b3,
                                              short* __restrict__ theta,
                                              short* __restrict__ phi,
                                              short* __restrict__ gT) {
  __shared__ short Lp[17408];   // 34816 B: dbuf K-loop [0..16383], oL epilogue [0..17407]
  int tid = threadIdx.x;
  int m0 = blockIdx.x * 128;   // pixel tile
  int nb = blockIdx.y;         // 0=theta 1=phi 2=g
  int b  = blockIdx.z;
  int lane = tid & 63, wid = tid >> 6;
  int col = lane & 15, quad = lane >> 4;
  int wm = (wid >> 1) * 64, wn = (wid & 1) * 64;
  const short* A = xt + ((size_t)b * 4096 + m0) * 256;
  const short* B = w123 + (size_t)nb * 128 * 256;
  short* a0 = Lp;           short* b0 = Lp + 4096;
  short* a1 = Lp + 8192;    short* b1_ = Lp + 12288;
  stage_chunk(a0, A, 256, tid);
  stage_chunk(b0, B, 256, tid);
  f32x4 acc[4][4];
  zero_acc(acc);
  for (int ks = 0; ks < 8; ++ks) {
    short* ac = (ks & 1) ? a1 : a0;
    short* an = (ks & 1) ? a0 : a1;
    short* bc = (ks & 1) ? b1_ : b0;
    short* bn = (ks & 1) ? b0 : b1_;
    __syncthreads();
    if (ks < 7) {
      stage_chunk(an, A + (ks + 1) * 32, 256, tid);
      stage_chunk(bn, B + (ks + 1) * 32, 256, tid);
    }
    bf16x8 af[4], bf_[4];
#pragma unroll
    for (int mi = 0; mi < 4; ++mi) af[mi] = lds8(&ac[(wm + mi * 16 + col) * 32 + quad * 8]);
#pragma unroll
    for (int ni = 0; ni < 4; ++ni) bf_[ni] = lds8(&bc[(wn + ni * 16 + col) * 32 + quad * 8]);
#pragma unroll
    for (int mi = 0; mi < 4; ++mi)
#pragma unroll
      for (int ni = 0; ni < 4; ++ni)
        acc[mi][ni] = MFMA16(af[mi], bf_[ni], acc[mi][ni], 0, 0, 0);
  }
  const float* bias = (nb == 0) ? b1 : (nb == 1 ? b2 : b3);
  __syncthreads();   // all K-loop LDS reads done; Lp reusable as oL
  short* oL = Lp;    // [128][136]
  if (nb < 2) {
#pragma unroll
    for (int mi = 0; mi < 4; ++mi)
#pragma unroll
      for (int ni = 0; ni < 4; ++ni) {
        float bv = bias[wn + ni * 16 + col];
#pragma unroll
        for (int r = 0; r < 4; ++r)
          oL[(wm + mi * 16 + quad * 4 + r) * 136 + wn + ni * 16 + col] = f2bs(acc[mi][ni][r] + bv);
      }
    __syncthreads();
    short* O = ((nb == 0) ? theta : phi) + ((size_t)b * 4096 + m0) * 128;
#pragma unroll
    for (int it = 0; it < 8; ++it) {
      int slot = it * 256 + tid;            // 2048 slots of 8 shorts
      int r = slot >> 4, cp = (slot & 15) * 8;
      *(bf16x8*)(O + (size_t)r * 128 + cp) = lds8(&oL[r * 136 + cp]);
    }
  } else {
    // transposed epilogue: oL[ch][pix]
#pragma unroll
    for (int mi = 0; mi < 4; ++mi)
#pragma unroll
      for (int ni = 0; ni < 4; ++ni) {
        float bv = bias[wn + ni * 16 + col];
#pragma unroll
        for (int r = 0; r < 4; ++r)
          oL[(wn + ni * 16 + col) * 136 + wm + mi * 16 + quad * 4 + r] = f2bs(acc[mi][ni][r] + bv);
      }
    __syncthreads();
    short* O = gT + (size_t)b * 128 * 4096 + m0;
#pragma unroll
    for (int it = 0; it < 8; ++it) {
      int slot = it * 256 + tid;
      int c = slot >> 4, p8 = (slot & 15) * 8;
      *(bf16x8*)(O + (size_t)c * 4096 + p8) = lds8(&oL[c * 136 + p8]);
    }
  }
}

// ---------------- K2: denom. S^T = phi.theta^T; dpart[b][ib][j] = sum_{i in ib} exp ----------------
__global__ __launch_bounds__(256, 2) void k_denom(const short* __restrict__ theta,
                                                  const short* __restrict__ phi,
                                                  float* __restrict__ dpart) {
  __shared__ short L[16384];   // theta stage 32 KB, then phi dbuf 2 x 16 KB
  __shared__ float part[128];
  int tid = threadIdx.x;
  int ib = blockIdx.x, jc = blockIdx.y, b = blockIdx.z;
  int lane = tid & 63, wid = tid >> 6;
  int col = lane & 15, quad = lane >> 4;
  int wmj = (wid & 1) * 32;    // m = j
  int wni = (wid >> 1) * 64;   // n = i
  const short* TH = theta + ((size_t)b * 4096 + ib * 128) * 128;
  const short* PH = phi + ((size_t)b * 4096 + (size_t)jc * 1024) * 128;
  float* D = dpart + ((size_t)(b * 32 + ib)) * 4096 + jc * 1024;
  // theta [128 i][128 k] -> B-fragments in registers
#pragma unroll
  for (int ks = 0; ks < 4; ++ks) stage_chunk(L + ks * 4096, TH + ks * 32, 128, tid);
  __syncthreads();
  bf16x8 bth[4][4];
#pragma unroll
  for (int ks = 0; ks < 4; ++ks)
#pragma unroll
    for (int ni = 0; ni < 4; ++ni)
      bth[ks][ni] = lds8(&L[ks * 4096 + (wni + ni * 16 + col) * 32 + quad * 8]);
  __syncthreads();
  // prologue: stage phi(0)
#pragma unroll
  for (int ks = 0; ks < 4; ++ks) stage_chunk64(L + ks * 2048, PH + ks * 32, 128, tid);
  for (int jt = 0; jt < 16; ++jt) {
    short* phc = L + (jt & 1) * 8192;
    short* phn = L + ((jt & 1) ^ 1) * 8192;
    __syncthreads();   // stage(jt) complete; part readers of jt-1 done
    if (jt < 15) {
      const short* PHn = PH + (size_t)(jt + 1) * 64 * 128;
#pragma unroll
      for (int ks = 0; ks < 4; ++ks) stage_chunk64(phn + ks * 2048, PHn + ks * 32, 128, tid);
    }
    f32x4 s[2][4];
#pragma unroll
    for (int mi = 0; mi < 2; ++mi)
#pragma unroll
      for (int ni = 0; ni < 4; ++ni) s[mi][ni] = (f32x4){0.f, 0.f, 0.f, 0.f};
#pragma unroll
    for (int ks = 0; ks < 4; ++ks) {
      bf16x8 ap[2];
#pragma unroll
      for (int mi = 0; mi < 2; ++mi) ap[mi] = lds8(&phc[ks * 2048 + (wmj + mi * 16 + col) * 32 + quad * 8]);
#pragma unroll
      for (int mi = 0; mi < 2; ++mi)
#pragma unroll
        for (int ni = 0; ni < 4; ++ni)
          s[mi][ni] = MFMA16(ap[mi], bth[ks][ni], s[mi][ni], 0, 0, 0);
    }
    // per-wave i-reduction; unique writer per part slot (no atomics)
#pragma unroll
    for (int mi = 0; mi < 2; ++mi)
#pragma unroll
      for (int r = 0; r < 4; ++r) {
        float ps = __expf(s[mi][0][r]) + __expf(s[mi][1][r]) +
                   __expf(s[mi][2][r]) + __expf(s[mi][3][r]);
        ps += __shfl_xor(ps, 1, 16);
        ps += __shfl_xor(ps, 2, 16);
        ps += __shfl_xor(ps, 4, 16);
        ps += __shfl_xor(ps, 8, 16);
        if (col == 0) part[(wid >> 1) * 64 + wmj + mi * 16 + quad * 4 + r] = ps;
      }
    __syncthreads();
    if (tid < 64) D[jt * 64 + tid] = part[tid] + part[64 + tid];
  }
}

// ---------------- K3: fused S^T recompute + exp*dinv -> P (b64 writes) + PV ----------------
// LDS (shorts): ph 0..8191, gp0 8192..16383, gp1 16384..24575, pP 24576..33279, dinv 33280..35327
__global__ __launch_bounds__(256, 2) void k_attn(const short* __restrict__ theta,
                                                 const short* __restrict__ phi,
                                                 const short* __restrict__ gT,
                                                 const float* __restrict__ dpart,
                                                 short* __restrict__ ypart) {
  __shared__ short L[35328];   // 70656 B -> 2 blocks/CU
  int tid = threadIdx.x;
  int ib = blockIdx.x, jc = blockIdx.y, b = blockIdx.z;
  int lane = tid & 63, wid = tid >> 6;
  int col = lane & 15, quad = lane >> 4;
  int wmj = (wid & 1) * 32;    // S^T m = j
  int wni = (wid >> 1) * 64;   // S^T n = i
  int wmi = (wid >> 1) * 64;   // PV m = i
  int wnc = (wid & 1) * 64;    // PV n = c
  const short* TH = theta + ((size_t)b * 4096 + ib * 128) * 128;
  const short* PH = phi + ((size_t)b * 4096 + (size_t)jc * 1024) * 128;
  const short* GT = gT + (size_t)b * 128 * 4096 + jc * 1024;
  short* ph = L;
  short* gp0 = L + 8192;
  short* gp1 = L + 16384;
  short* pP = L + 24576;       // [128 i][68 j]
  float* dinv = (float*)(L + 33280);   // 1024 floats
  // denominator reduce: 32 partials -> 1/d, into LDS (one-time)
  {
    int j4 = tid * 4;
    f32x4 ds = {0.f, 0.f, 0.f, 0.f};
    for (int ibb = 0; ibb < 32; ++ibb)
      ds += *(const f32x4*)(dpart + ((size_t)(b * 32 + ibb)) * 4096 + jc * 1024 + j4);
    f32x4 di;
#pragma unroll
    for (int e = 0; e < 4; ++e) di[e] = 1.0f / ds[e];
    *(f32x4*)(dinv + j4) = di;
  }
  // theta -> B-fragments (staged across ph+gp0 regions, then re-used)
#pragma unroll
  for (int ks = 0; ks < 4; ++ks) stage_chunk(L + ks * 4096, TH + ks * 32, 128, tid);
  __syncthreads();
  bf16x8 bth[4][4];
#pragma unroll
  for (int ks = 0; ks < 4; ++ks)
#pragma unroll
    for (int ni = 0; ni < 4; ++ni)
      bth[ks][ni] = lds8(&L[ks * 4096 + (wni + ni * 16 + col) * 32 + quad * 8]);
  __syncthreads();
  // prologue: phi(0) + gT(0)
#pragma unroll
  for (int ks = 0; ks < 4; ++ks) stage_chunk64(ph + ks * 2048, PH + ks * 32, 128, tid);
#pragma unroll
  for (int s = 0; s < 2; ++s) stage_chunk(gp0 + s * 4096, GT + s * 32, 4096, tid);
  f32x4 accy[4][4];
  zero_acc(accy);
  for (int jt = 0; jt < 16; ++jt) {
    short* gpc = (jt & 1) ? gp1 : gp0;
    short* gpn = (jt & 1) ? gp0 : gp1;
    __syncthreads();   // phi(jt)/gT(jt) staged; prev-iter pP reads done
    f32x4 dv[2];
#pragma unroll
    for (int mi = 0; mi < 2; ++mi)
      dv[mi] = *(const f32x4*)(dinv + jt * 64 + wmj + mi * 16 + quad * 4);
    // S^T = phi . theta^T  (m=j 64, n=i 128, K=128)
    f32x4 s[2][4];
#pragma unroll
    for (int mi = 0; mi < 2; ++mi)
#pragma unroll
      for (int ni = 0; ni < 4; ++ni) s[mi][ni] = (f32x4){0.f, 0.f, 0.f, 0.f};
#pragma unroll
    for (int ks = 0; ks < 4; ++ks) {
      bf16x8 ap[2];
#pragma unroll
      for (int mi = 0; mi < 2; ++mi) ap[mi] = lds8(&ph[ks * 2048 + (wmj + mi * 16 + col) * 32 + quad * 8]);
#pragma unroll
      for (int mi = 0; mi < 2; ++mi)
#pragma unroll
        for (int ni = 0; ni < 4; ++ni)
          s[mi][ni] = MFMA16(ap[mi], bth[ks][ni], s[mi][ni], 0, 0, 0);
    }
    // P[i][j] = exp(S)*dinv[j] — contiguous b64 writes, conflict-free
#pragma unroll
    for (int mi = 0; mi < 2; ++mi) {
      int j0 = wmj + mi * 16 + quad * 4;
#pragma unroll
      for (int ni = 0; ni < 4; ++ni) {
        int i = wni + ni * 16 + col;
        bf16x4 pv;
#pragma unroll
        for (int r = 0; r < 4; ++r) pv[r] = f2bs(__expf(s[mi][ni][r]) * dv[mi][r]);
        *(bf16x4*)(pP + i * 68 + j0) = pv;
      }
    }
    __syncthreads();   // pP visible; phi reads done
    if (jt < 15) {
      const short* PHn = PH + (size_t)(jt + 1) * 64 * 128;
#pragma unroll
      for (int ks = 0; ks < 4; ++ks) stage_chunk64(ph + ks * 2048, PHn + ks * 32, 128, tid);
      const short* GTn = GT + (jt + 1) * 64;
#pragma unroll
      for (int s2 = 0; s2 < 2; ++s2) stage_chunk(gpn + s2 * 4096, GTn + s2 * 32, 4096, tid);
    }
    // Y[i][c] += P . gT^T  (m=i 128, n=c 128, K=64)
#pragma unroll
    for (int ksj = 0; ksj < 2; ++ksj) {
      bf16x8 ap2[4], bg[4];
#pragma unroll
      for (int mi = 0; mi < 4; ++mi) ap2[mi] = lds8(&pP[(wmi + mi * 16 + col) * 68 + ksj * 32 + quad * 8]);
#pragma unroll
      for (int ni = 0; ni < 4; ++ni) bg[ni] = lds8(&gpc[ksj * 4096 + (wnc + ni * 16 + col) * 32 + quad * 8]);
#pragma unroll
      for (int mi = 0; mi < 4; ++mi)
#pragma unroll
        for (int ni = 0; ni < 4; ++ni)
          accy[mi][ni] = MFMA16(ap2[mi], bg[ni], accy[mi][ni], 0, 0, 0);
    }
  }
  // epilogue: bf16 partial via pP repack (stride 128), coalesced 16 B stores
  short* Yp = ypart + ((size_t)(jc * 4 + b) * 4096 + (size_t)ib * 128) * 128;
#pragma unroll
  for (int half = 0; half < 2; ++half) {
    __syncthreads();
    if ((wid >> 1) == half) {
#pragma unroll
      for (int mi = 0; mi < 4; ++mi)
#pragma unroll
        for (int ni = 0; ni < 4; ++ni)
#pragma unroll
          for (int r = 0; r < 4; ++r)
            pP[(mi * 16 + quad * 4 + r) * 128 + wnc + ni * 16 + col] = f2bs(accy[mi][ni][r]);
    }
    __syncthreads();
#pragma unroll
    for (int it = 0; it < 4; ++it) {
      int slot = it * 256 + tid;        // 1024 slots of 8 shorts over [64][128]
      int r = slot >> 4, c8 = (slot & 15) * 8;
      *(bf16x8*)(Yp + (size_t)(half * 64 + r) * 128 + c8) = lds8(&pP[r * 128 + c8]);
    }
  }
}

// ---------------- K4: out[o][i] = w4 . (sum of 4 bf16 ypart partials) + b4 + x ----------------
__global__ __launch_bounds__(256) void k_out(const short* __restrict__ ypart,
                                             const float* __restrict__ w4,
                                             const float* __restrict__ b4,
                                             const float* __restrict__ x,
                                             float* __restrict__ out) {
  __shared__ short wL[4 * 4096];   // [ksc][o][32c]
  __shared__ short yL[4 * 4096];   // [ksc][i][32c]
  __shared__ float bLs[128];
  int tid = threadIdx.x;
  int ibk = blockIdx.x, ob = blockIdx.y, b = blockIdx.z;
  int o0 = ob * 128, i0 = ibk * 128;
  int lane = tid & 63, wid = tid >> 6;
  int col = lane & 15, quad = lane >> 4;
  int wm = (wid >> 1) * 64, wn = (wid & 1) * 64;
#pragma unroll
  for (int it = 0; it < 16; ++it) {
    int slot = it * 256 + tid;          // 4096 float4 slots over w4 [128][128]
    int r = slot >> 5, c4 = (slot & 31) * 4;
    int ks = c4 >> 5, cr = c4 & 31;
    f32x4 wv = *(const f32x4*)(w4 + (size_t)(o0 + r) * 128 + c4);
    bf16x4 wp;
#pragma unroll
    for (int e = 0; e < 4; ++e) wp[e] = f2bs(wv[e]);
    *(bf16x4*)&wL[ks * 4096 + r * 32 + cr] = wp;
  }
#pragma unroll
  for (int it = 0; it < 8; ++it) {
    int slot = it * 256 + tid;          // 2048 slots of 8 over y [128][128]
    int r = slot >> 4, c8 = (slot & 15) * 8;
    int ks = c8 >> 5, cr = c8 & 31;
    float a8[8];
#pragma unroll
    for (int e = 0; e < 8; ++e) a8[e] = 0.f;
#pragma unroll
    for (int p = 0; p < 4; ++p) {
      bf16x8 v = *(const bf16x8*)(ypart + ((size_t)(p * 4 + b) * 4096 + i0 + r) * 128 + c8);
#pragma unroll
      for (int e = 0; e < 8; ++e) a8[e] += bs2f(v[e]);
    }
    bf16x8 yv;
#pragma unroll
    for (int e = 0; e < 8; ++e) yv[e] = f2bs(a8[e]);
    *(bf16x8*)&yL[ks * 4096 + r * 32 + cr] = yv;
  }
  if (tid < 128) bLs[tid] = b4[o0 + tid];
  __syncthreads();
  f32x4 acc[4][4];
  zero_acc(acc);
#pragma unroll
  for (int ks = 0; ks < 4; ++ks) {
    bf16x8 af[4], bf_[4];
#pragma unroll
    for (int mi = 0; mi < 4; ++mi) af[mi] = lds8(&wL[ks * 4096 + (wm + mi * 16 + col) * 32 + quad * 8]);
#pragma unroll
    for (int ni = 0; ni < 4; ++ni) bf_[ni] = lds8(&yL[ks * 4096 + (wn + ni * 16 + col) * 32 + quad * 8]);
#pragma unroll
    for (int mi = 0; mi < 4; ++mi)
#pragma unroll
      for (int ni = 0; ni < 4; ++ni)
        acc[mi][ni] = MFMA16(af[mi], bf_[ni], acc[mi][ni], 0, 0, 0);
  }
  const float* X = x + ((size_t)b * 256 + o0) * 4096 + i0;
  float* O = out + ((size_t)b * 256 + o0) * 4096 + i0;
#pragma unroll
  for (int mi = 0; mi < 4; ++mi)
#pragma unroll
    for (int ni = 0; ni < 4; ++ni)
#pragma unroll
      for (int r = 0; r < 4; ++r) {
        int o = wm + mi * 16 + quad * 4 + r;
        int i = wn + ni * 16 + col;
        O[(size_t)o * 4096 + i] = acc[mi][ni][r] + X[(size_t)o * 4096 + i] + bLs[o];
      }
}

extern "C" void kernel_launch(void* const* d_in, const int* in_sizes, int n_in,
                              void* d_out, int out_size, void* d_ws, size_t ws_size,
                              hipStream_t stream) {
  const float* x  = (const float*)d_in[0];
  const float* w1 = (const float*)d_in[1];
  const float* b1 = (const float*)d_in[2];
  const float* w2 = (const float*)d_in[3];
  const float* b2 = (const float*)d_in[4];
  const float* w3 = (const float*)d_in[5];
  const float* b3 = (const float*)d_in[6];
  const float* w4 = (const float*)d_in[7];
  const float* b4 = (const float*)d_in[8];
  char* ws = (char*)d_ws;
  short* xt    = (short*)(ws + 0);          // 8,388,608
  short* w123  = (short*)(ws + 8388608);    //   196,608
  short* theta = (short*)(ws + 8585216);    // 4,194,304
  short* phi   = (short*)(ws + 12779520);   // 4,194,304
  short* gT    = (short*)(ws + 16973824);   // 4,194,304
  float* dpart = (float*)(ws + 21168128);   // 2,097,152
  short* ypart = (short*)(ws + 23265280);   // 16,777,216 (end 40,042,496)
  float* out   = (float*)d_out;
  (void)in_sizes; (void)n_in; (void)out_size; (void)ws_size;

  k_prep<<<dim3(64, 5, 4), dim3(256), 0, stream>>>(x, w1, w2, w3, xt, w123);
  k_proj<<<dim3(32, 3, 4), dim3(256), 0, stream>>>(xt, w123, b1, b2, b3, theta, phi, gT);
  k_denom<<<dim3(32, 4, 4), dim3(256), 0, stream>>>(theta, phi, dpart);
  k_attn<<<dim3(32, 4, 4), dim3(256), 0, stream>>>(theta, phi, gT, dpart, ypart);
  k_out<<<dim3(32, 2, 4), dim3(256), 0, stream>>>(ypart, w4, b4, x, out);
}

// Round 6
// 187.708 us; speedup vs baseline: 1.3159x; 1.0766x over previous
//
#include <hip/hip_runtime.h>

#define DEVI __device__ __forceinline__

typedef __attribute__((ext_vector_type(8))) short bf16x8;
typedef __attribute__((ext_vector_type(4))) short bf16x4;
typedef __attribute__((ext_vector_type(4))) float f32x4;

#define MFMA16 __builtin_amdgcn_mfma_f32_16x16x32_bf16

DEVI short f2bs(float f) {  // fp32 -> bf16 bits, round-nearest-even
  union { float f; unsigned u; } v; v.f = f;
  unsigned r = v.u + 0x7fffu + ((v.u >> 16) & 1u);
  return (short)(r >> 16);
}
DEVI float bs2f(short s) {
  union { unsigned u; float f; } v; v.u = ((unsigned)(unsigned short)s) << 16;
  return v.f;
}

DEVI void gload_lds16(const short* g, short* lds) {
  __builtin_amdgcn_global_load_lds(
      (const __attribute__((address_space(1))) unsigned int*)g,
      (__attribute__((address_space(3))) unsigned int*)lds, 16, 0, 0);
}

// stage a [128 rows][32 k] bf16 chunk (8 KB) packed into LDS. 2 instrs/thread.
DEVI void stage_chunk(short* lds, const short* g, int ldg, int tid) {
#pragma unroll
  for (int it = 0; it < 2; ++it) {
    int slot = it * 256 + tid;          // 0..511
    int row  = slot >> 2;               // 4 lanes per 64 B row
    int ko   = (slot & 3) << 3;
    gload_lds16(g + (size_t)row * ldg + ko, lds + slot * 8);
  }
}

// stage a [64 rows][32 k] bf16 chunk (4 KB). 1 instr/thread.
DEVI void stage_chunk64(short* lds, const short* g, int ldg, int tid) {
  int row = tid >> 2, ko = (tid & 3) << 3;
  gload_lds16(g + (size_t)row * ldg + ko, lds + tid * 8);
}

DEVI bf16x8 lds8(const short* p) { return *(const bf16x8*)p; }

DEVI void zero_acc(f32x4 (&a)[4][4]) {
  f32x4 z = {0.f, 0.f, 0.f, 0.f};
#pragma unroll
  for (int i = 0; i < 4; ++i)
#pragma unroll
    for (int j = 0; j < 4; ++j) a[i][j] = z;
}

// ---------------- K0: x -> xt (transpose+cast) and w1/w2/w3 -> w123 bf16 ----------------
__global__ __launch_bounds__(256) void k_prep(const float* __restrict__ x,
                                              const float* __restrict__ w1,
                                              const float* __restrict__ w2,
                                              const float* __restrict__ w3,
                                              short* __restrict__ xt,
                                              short* __restrict__ w123) {
  int tid = threadIdx.x;
  if (blockIdx.y == 4) {   // weight cast
    int lin = blockIdx.z * 64 + blockIdx.x;
    for (int i = lin * 256 + tid; i < 384 * 256; i += 65536) {
      int r = i >> 8;
      const float* w = (r < 128) ? w1 : (r < 256 ? w2 : w3);
      w123[i] = f2bs(w[(size_t)(r & 127) * 256 + (i & 255)]);
    }
    return;
  }
  __shared__ float t[64][65];
  int b = blockIdx.z;
  int c0 = blockIdx.y * 64;
  int p0 = blockIdx.x * 64;
  const float* xb = x + (size_t)b * 256 * 4096;
#pragma unroll
  for (int i = 0; i < 16; ++i) {
    int idx = i * 256 + tid;
    int c = idx >> 6, p = idx & 63;
    t[p][c] = xb[(size_t)(c0 + c) * 4096 + p0 + p];
  }
  __syncthreads();
  short* xtb = xt + ((size_t)b * 4096 + p0) * 256 + c0;
#pragma unroll
  for (int i = 0; i < 16; ++i) {
    int idx = i * 256 + tid;
    int p = idx >> 6, c = idx & 63;
    xtb[(size_t)p * 256 + c] = f2bs(t[p][c]);
  }
}

// ---------------- K1: projections (dbuf). theta/phi [pix][ch]; g -> gT [ch][pix] ----------------
__global__ __launch_bounds__(256) void k_proj(const short* __restrict__ xt,
                                              const short* __restrict__ w123,
                                              const float* __restrict__ b1,
                                              const float* __restrict__ b2,
                                              const float* __restrict__ b3,
                                              short* __restrict__ theta,
                                              short* __restrict__ phi,
                                              short* __restrict__ gT) {
  __shared__ short Lp[17408];   // 34816 B: dbuf K-loop [0..16383], oL epilogue [0..17407]
  int tid = threadIdx.x;
  int m0 = blockIdx.x * 128;   // pixel tile
  int nb = blockIdx.y;         // 0=theta 1=phi 2=g
  int b  = blockIdx.z;
  int lane = tid & 63, wid = tid >> 6;
  int col = lane & 15, quad = lane >> 4;
  int wm = (wid >> 1) * 64, wn = (wid & 1) * 64;
  const short* A = xt + ((size_t)b * 4096 + m0) * 256;
  const short* B = w123 + (size_t)nb * 128 * 256;
  short* a0 = Lp;           short* b0 = Lp + 4096;
  short* a1 = Lp + 8192;    short* b1_ = Lp + 12288;
  stage_chunk(a0, A, 256, tid);
  stage_chunk(b0, B, 256, tid);
  f32x4 acc[4][4];
  zero_acc(acc);
  for (int ks = 0; ks < 8; ++ks) {
    short* ac = (ks & 1) ? a1 : a0;
    short* an = (ks & 1) ? a0 : a1;
    short* bc = (ks & 1) ? b1_ : b0;
    short* bn = (ks & 1) ? b0 : b1_;
    __syncthreads();
    if (ks < 7) {
      stage_chunk(an, A + (ks + 1) * 32, 256, tid);
      stage_chunk(bn, B + (ks + 1) * 32, 256, tid);
    }
    bf16x8 af[4], bf_[4];
#pragma unroll
    for (int mi = 0; mi < 4; ++mi) af[mi] = lds8(&ac[(wm + mi * 16 + col) * 32 + quad * 8]);
#pragma unroll
    for (int ni = 0; ni < 4; ++ni) bf_[ni] = lds8(&bc[(wn + ni * 16 + col) * 32 + quad * 8]);
#pragma unroll
    for (int mi = 0; mi < 4; ++mi)
#pragma unroll
      for (int ni = 0; ni < 4; ++ni)
        acc[mi][ni] = MFMA16(af[mi], bf_[ni], acc[mi][ni], 0, 0, 0);
  }
  const float* bias = (nb == 0) ? b1 : (nb == 1 ? b2 : b3);
  __syncthreads();   // all K-loop LDS reads done; Lp reusable as oL
  short* oL = Lp;    // [128][136]
  if (nb < 2) {
#pragma unroll
    for (int mi = 0; mi < 4; ++mi)
#pragma unroll
      for (int ni = 0; ni < 4; ++ni) {
        float bv = bias[wn + ni * 16 + col];
#pragma unroll
        for (int r = 0; r < 4; ++r)
          oL[(wm + mi * 16 + quad * 4 + r) * 136 + wn + ni * 16 + col] = f2bs(acc[mi][ni][r] + bv);
      }
    __syncthreads();
    short* O = ((nb == 0) ? theta : phi) + ((size_t)b * 4096 + m0) * 128;
#pragma unroll
    for (int it = 0; it < 8; ++it) {
      int slot = it * 256 + tid;            // 2048 slots of 8 shorts
      int r = slot >> 4, cp = (slot & 15) * 8;
      *(bf16x8*)(O + (size_t)r * 128 + cp) = lds8(&oL[r * 136 + cp]);
    }
  } else {
    // transposed epilogue: oL[ch][pix]
#pragma unroll
    for (int mi = 0; mi < 4; ++mi)
#pragma unroll
      for (int ni = 0; ni < 4; ++ni) {
        float bv = bias[wn + ni * 16 + col];
#pragma unroll
        for (int r = 0; r < 4; ++r)
          oL[(wn + ni * 16 + col) * 136 + wm + mi * 16 + quad * 4 + r] = f2bs(acc[mi][ni][r] + bv);
      }
    __syncthreads();
    short* O = gT + (size_t)b * 128 * 4096 + m0;
#pragma unroll
    for (int it = 0; it < 8; ++it) {
      int slot = it * 256 + tid;
      int c = slot >> 4, p8 = (slot & 15) * 8;
      *(bf16x8*)(O + (size_t)c * 4096 + p8) = lds8(&oL[c * 136 + p8]);
    }
  }
}

// ---------------- K2: denom. S^T = phi.theta^T; dpart[b][ib][j] = sum_{i in ib} exp ----------------
__global__ __launch_bounds__(256, 2) void k_denom(const short* __restrict__ theta,
                                                  const short* __restrict__ phi,
                                                  float* __restrict__ dpart) {
  __shared__ short L[16384];   // theta stage 32 KB, then phi dbuf 2 x 16 KB
  __shared__ float part[128];
  int tid = threadIdx.x;
  int ib = blockIdx.x, jc = blockIdx.y, b = blockIdx.z;
  int lane = tid & 63, wid = tid >> 6;
  int col = lane & 15, quad = lane >> 4;
  int wmj = (wid & 1) * 32;    // m = j
  int wni = (wid >> 1) * 64;   // n = i
  const short* TH = theta + ((size_t)b * 4096 + ib * 128) * 128;
  const short* PH = phi + ((size_t)b * 4096 + (size_t)jc * 1024) * 128;
  float* D = dpart + ((size_t)(b * 32 + ib)) * 4096 + jc * 1024;
  // theta [128 i][128 k] -> B-fragments in registers
#pragma unroll
  for (int ks = 0; ks < 4; ++ks) stage_chunk(L + ks * 4096, TH + ks * 32, 128, tid);
  __syncthreads();
  bf16x8 bth[4][4];
#pragma unroll
  for (int ks = 0; ks < 4; ++ks)
#pragma unroll
    for (int ni = 0; ni < 4; ++ni)
      bth[ks][ni] = lds8(&L[ks * 4096 + (wni + ni * 16 + col) * 32 + quad * 8]);
  __syncthreads();
  // prologue: stage phi(0)
#pragma unroll
  for (int ks = 0; ks < 4; ++ks) stage_chunk64(L + ks * 2048, PH + ks * 32, 128, tid);
  for (int jt = 0; jt < 16; ++jt) {
    short* phc = L + (jt & 1) * 8192;
    short* phn = L + ((jt & 1) ^ 1) * 8192;
    __syncthreads();   // stage(jt) complete; part readers of jt-1 done
    if (jt < 15) {
      const short* PHn = PH + (size_t)(jt + 1) * 64 * 128;
#pragma unroll
      for (int ks = 0; ks < 4; ++ks) stage_chunk64(phn + ks * 2048, PHn + ks * 32, 128, tid);
    }
    f32x4 s[2][4];
#pragma unroll
    for (int mi = 0; mi < 2; ++mi)
#pragma unroll
      for (int ni = 0; ni < 4; ++ni) s[mi][ni] = (f32x4){0.f, 0.f, 0.f, 0.f};
#pragma unroll
    for (int ks = 0; ks < 4; ++ks) {
      bf16x8 ap[2];
#pragma unroll
      for (int mi = 0; mi < 2; ++mi) ap[mi] = lds8(&phc[ks * 2048 + (wmj + mi * 16 + col) * 32 + quad * 8]);
#pragma unroll
      for (int mi = 0; mi < 2; ++mi)
#pragma unroll
        for (int ni = 0; ni < 4; ++ni)
          s[mi][ni] = MFMA16(ap[mi], bth[ks][ni], s[mi][ni], 0, 0, 0);
    }
    // per-wave i-reduction; unique writer per part slot (no atomics)
#pragma unroll
    for (int mi = 0; mi < 2; ++mi)
#pragma unroll
      for (int r = 0; r < 4; ++r) {
        float ps = __expf(s[mi][0][r]) + __expf(s[mi][1][r]) +
                   __expf(s[mi][2][r]) + __expf(s[mi][3][r]);
        ps += __shfl_xor(ps, 1, 16);
        ps += __shfl_xor(ps, 2, 16);
        ps += __shfl_xor(ps, 4, 16);
        ps += __shfl_xor(ps, 8, 16);
        if (col == 0) part[(wid >> 1) * 64 + wmj + mi * 16 + quad * 4 + r] = ps;
      }
    __syncthreads();
    if (tid < 64) D[jt * 64 + tid] = part[tid] + part[64 + tid];
  }
}

// ---------------- K2b: dinv[b][j] = 1 / sum_ib dpart[b][ib][j] ----------------
__global__ __launch_bounds__(256) void k_dred(const float* __restrict__ dpart,
                                              float* __restrict__ dinv) {
  int b = blockIdx.x >> 2, jb = blockIdx.x & 3;
  int j4 = jb * 1024 + threadIdx.x * 4;
  f32x4 s = {0.f, 0.f, 0.f, 0.f};
  for (int ib = 0; ib < 32; ++ib)
    s += *(const f32x4*)(dpart + ((size_t)(b * 32 + ib)) * 4096 + j4);
  f32x4 r;
#pragma unroll
  for (int e = 0; e < 4; ++e) r[e] = 1.0f / s[e];
  *(f32x4*)(dinv + (size_t)b * 4096 + j4) = r;
}

// ---------------- K3: fused S^T recompute + exp*dinv -> P (swizzled b64) + PV ----------------
// LDS (shorts): ph0 0..8191, ph1 8192..16383, gp0 16384..24575, gp1 24576..32767,
//               pP 32768..40959 ([128 i][64 j], 8-short blocks XOR-swizzled by i&7) = 80 KB exact
__global__ __launch_bounds__(256, 2) void k_attn(const short* __restrict__ theta,
                                                 const short* __restrict__ phi,
                                                 const short* __restrict__ gT,
                                                 const float* __restrict__ dinv,
                                                 short* __restrict__ ypart) {
  __shared__ short L[40960];   // 81920 B -> 2 blocks/CU
  int tid = threadIdx.x;
  int ib = blockIdx.x, jc = blockIdx.y, b = blockIdx.z;
  int lane = tid & 63, wid = tid >> 6;
  int col = lane & 15, quad = lane >> 4;
  int wmj = (wid & 1) * 32;    // S^T m = j
  int wni = (wid >> 1) * 64;   // S^T n = i; also PV m = i
  int wnc = (wid & 1) * 64;    // PV n = c
  const short* TH = theta + ((size_t)b * 4096 + ib * 128) * 128;
  const short* PH = phi + ((size_t)b * 4096 + (size_t)jc * 1024) * 128;
  const short* GT = gT + (size_t)b * 128 * 4096 + jc * 1024;
  const float* DI = dinv + (size_t)b * 4096 + jc * 1024;
  short* pP = L + 32768;
  // theta [128 i][128 k] -> B-fragments (staged into ph0+ph1 region, then released)
#pragma unroll
  for (int ks = 0; ks < 4; ++ks) stage_chunk(L + ks * 4096, TH + ks * 32, 128, tid);
  __syncthreads();
  bf16x8 bth[4][4];
#pragma unroll
  for (int ks = 0; ks < 4; ++ks)
#pragma unroll
    for (int ni = 0; ni < 4; ++ni)
      bth[ks][ni] = lds8(&L[ks * 4096 + (wni + ni * 16 + col) * 32 + quad * 8]);
  __syncthreads();
  // prologue: phi(0) -> ph0, gT(0) -> gp0
#pragma unroll
  for (int ks = 0; ks < 4; ++ks) stage_chunk64(L + ks * 2048, PH + ks * 32, 128, tid);
#pragma unroll
  for (int s = 0; s < 2; ++s) stage_chunk(L + 16384 + s * 4096, GT + s * 32, 4096, tid);
  f32x4 accy[4][4];
  zero_acc(accy);
  for (int jt = 0; jt < 16; ++jt) {
    int cur = jt & 1;
    short* phc = L + cur * 8192;
    short* phn = L + (cur ^ 1) * 8192;
    short* gpc = L + 16384 + cur * 8192;
    short* gpn = L + 16384 + (cur ^ 1) * 8192;
    __syncthreads();   // phi(jt)/gT(jt) staged; prev-iter pP reads done
    if (jt < 15) {     // prefetch phi(jt+1) — covered by S+exp window
      const short* PHn = PH + (size_t)(jt + 1) * 64 * 128;
#pragma unroll
      for (int ks = 0; ks < 4; ++ks) stage_chunk64(phn + ks * 2048, PHn + ks * 32, 128, tid);
    }
    f32x4 dv[2];
#pragma unroll
    for (int mi = 0; mi < 2; ++mi)
      dv[mi] = *(const f32x4*)(DI + jt * 64 + wmj + mi * 16 + quad * 4);
    // S^T = phi . theta^T  (m=j 64, n=i 128, K=128)
    f32x4 s[2][4];
#pragma unroll
    for (int mi = 0; mi < 2; ++mi)
#pragma unroll
      for (int ni = 0; ni < 4; ++ni) s[mi][ni] = (f32x4){0.f, 0.f, 0.f, 0.f};
#pragma unroll
    for (int ks = 0; ks < 4; ++ks) {
      bf16x8 ap[2];
#pragma unroll
      for (int mi = 0; mi < 2; ++mi) ap[mi] = lds8(&phc[ks * 2048 + (wmj + mi * 16 + col) * 32 + quad * 8]);
#pragma unroll
      for (int mi = 0; mi < 2; ++mi)
#pragma unroll
        for (int ni = 0; ni < 4; ++ni)
          s[mi][ni] = MFMA16(ap[mi], bth[ks][ni], s[mi][ni], 0, 0, 0);
    }
    // P[i][j] = exp(S)*dinv[j] — b64 writes into XOR-swizzled [128][64]
#pragma unroll
    for (int mi = 0; mi < 2; ++mi) {
      int j0 = wmj + mi * 16 + quad * 4;
      int blk = j0 >> 3, off = j0 & 7;
#pragma unroll
      for (int ni = 0; ni < 4; ++ni) {
        int i = wni + ni * 16 + col;
        bf16x4 pv;
#pragma unroll
        for (int r = 0; r < 4; ++r) pv[r] = f2bs(__expf(s[mi][ni][r]) * dv[mi][r]);
        *(bf16x4*)(pP + i * 64 + ((blk ^ (i & 7)) << 3) + off) = pv;
      }
    }
    __syncthreads();   // pP visible; phi(jt) reads done
    if (jt < 15) {     // prefetch gT(jt+1) — covered by PV window
      const short* GTn = GT + (jt + 1) * 64;
#pragma unroll
      for (int s2 = 0; s2 < 2; ++s2) stage_chunk(gpn + s2 * 4096, GTn + s2 * 32, 4096, tid);
    }
    // Y[i][c] += P . gT^T  (m=i 128, n=c 128, K=64)
#pragma unroll
    for (int ksj = 0; ksj < 2; ++ksj) {
      bf16x8 ap2[4], bg[4];
#pragma unroll
      for (int mi = 0; mi < 4; ++mi) {
        int i = wni + mi * 16 + col;
        ap2[mi] = lds8(&pP[i * 64 + (((ksj * 4 + quad) ^ (i & 7)) << 3)]);
      }
#pragma unroll
      for (int ni = 0; ni < 4; ++ni) bg[ni] = lds8(&gpc[ksj * 4096 + (wnc + ni * 16 + col) * 32 + quad * 8]);
#pragma unroll
      for (int mi = 0; mi < 4; ++mi)
#pragma unroll
        for (int ni = 0; ni < 4; ++ni)
          accy[mi][ni] = MFMA16(ap2[mi], bg[ni], accy[mi][ni], 0, 0, 0);
    }
  }
  // epilogue: bf16 partial via pP repack ([64][128]), coalesced 16 B stores
  short* Yp = ypart + ((size_t)(jc * 4 + b) * 4096 + (size_t)ib * 128) * 128;
#pragma unroll
  for (int half = 0; half < 2; ++half) {
    __syncthreads();
    if ((wid >> 1) == half) {
#pragma unroll
      for (int mi = 0; mi < 4; ++mi)
#pragma unroll
        for (int ni = 0; ni < 4; ++ni)
#pragma unroll
          for (int r = 0; r < 4; ++r)
            pP[(mi * 16 + quad * 4 + r) * 128 + wnc + ni * 16 + col] = f2bs(accy[mi][ni][r]);
    }
    __syncthreads();
#pragma unroll
    for (int it = 0; it < 4; ++it) {
      int slot = it * 256 + tid;        // 1024 slots of 8 shorts over [64][128]
      int r = slot >> 4, c8 = (slot & 15) * 8;
      *(bf16x8*)(Yp + (size_t)(half * 64 + r) * 128 + c8) = lds8(&pP[r * 128 + c8]);
    }
  }
}

// ---------------- K4: out[o][i] = w4 . (sum of 4 bf16 ypart partials) + b4 + x ----------------
__global__ __launch_bounds__(256) void k_out(const short* __restrict__ ypart,
                                             const float* __restrict__ w4,
                                             const float* __restrict__ b4,
                                             const float* __restrict__ x,
                                             float* __restrict__ out) {
  __shared__ short wL[4 * 4096];   // [ksc][o][32c]
  __shared__ short yL[4 * 4096];   // [ksc][i][32c]
  __shared__ float bLs[128];
  int tid = threadIdx.x;
  int ibk = blockIdx.x, ob = blockIdx.y, b = blockIdx.z;
  int o0 = ob * 128, i0 = ibk * 128;
  int lane = tid & 63, wid = tid >> 6;
  int col = lane & 15, quad = lane >> 4;
  int wm = (wid >> 1) * 64, wn = (wid & 1) * 64;
#pragma unroll
  for (int it = 0; it < 16; ++it) {
    int slot = it * 256 + tid;          // 4096 float4 slots over w4 [128][128]
    int r = slot >> 5, c4 = (slot & 31) * 4;
    int ks = c4 >> 5, cr = c4 & 31;
    f32x4 wv = *(const f32x4*)(w4 + (size_t)(o0 + r) * 128 + c4);
    bf16x4 wp;
#pragma unroll
    for (int e = 0; e < 4; ++e) wp[e] = f2bs(wv[e]);
    *(bf16x4*)&wL[ks * 4096 + r * 32 + cr] = wp;
  }
#pragma unroll
  for (int it = 0; it < 8; ++it) {
    int slot = it * 256 + tid;          // 2048 slots of 8 over y [128][128]
    int r = slot >> 4, c8 = (slot & 15) * 8;
    int ks = c8 >> 5, cr = c8 & 31;
    float a8[8];
#pragma unroll
    for (int e = 0; e < 8; ++e) a8[e] = 0.f;
#pragma unroll
    for (int p = 0; p < 4; ++p) {
      bf16x8 v = *(const bf16x8*)(ypart + ((size_t)(p * 4 + b) * 4096 + i0 + r) * 128 + c8);
#pragma unroll
      for (int e = 0; e < 8; ++e) a8[e] += bs2f(v[e]);
    }
    bf16x8 yv;
#pragma unroll
    for (int e = 0; e < 8; ++e) yv[e] = f2bs(a8[e]);
    *(bf16x8*)&yL[ks * 4096 + r * 32 + cr] = yv;
  }
  if (tid < 128) bLs[tid] = b4[o0 + tid];
  __syncthreads();
  f32x4 acc[4][4];
  zero_acc(acc);
#pragma unroll
  for (int ks = 0; ks < 4; ++ks) {
    bf16x8 af[4], bf_[4];
#pragma unroll
    for (int mi = 0; mi < 4; ++mi) af[mi] = lds8(&wL[ks * 4096 + (wm + mi * 16 + col) * 32 + quad * 8]);
#pragma unroll
    for (int ni = 0; ni < 4; ++ni) bf_[ni] = lds8(&yL[ks * 4096 + (wn + ni * 16 + col) * 32 + quad * 8]);
#pragma unroll
    for (int mi = 0; mi < 4; ++mi)
#pragma unroll
      for (int ni = 0; ni < 4; ++ni)
        acc[mi][ni] = MFMA16(af[mi], bf_[ni], acc[mi][ni], 0, 0, 0);
  }
  const float* X = x + ((size_t)b * 256 + o0) * 4096 + i0;
  float* O = out + ((size_t)b * 256 + o0) * 4096 + i0;
#pragma unroll
  for (int mi = 0; mi < 4; ++mi)
#pragma unroll
    for (int ni = 0; ni < 4; ++ni)
#pragma unroll
      for (int r = 0; r < 4; ++r) {
        int o = wm + mi * 16 + quad * 4 + r;
        int i = wn + ni * 16 + col;
        O[(size_t)o * 4096 + i] = acc[mi][ni][r] + X[(size_t)o * 4096 + i] + bLs[o];
      }
}

extern "C" void kernel_launch(void* const* d_in, const int* in_sizes, int n_in,
                              void* d_out, int out_size, void* d_ws, size_t ws_size,
                              hipStream_t stream) {
  const float* x  = (const float*)d_in[0];
  const float* w1 = (const float*)d_in[1];
  const float* b1 = (const float*)d_in[2];
  const float* w2 = (const float*)d_in[3];
  const float* b2 = (const float*)d_in[4];
  const float* w3 = (const float*)d_in[5];
  const float* b3 = (const float*)d_in[6];
  const float* w4 = (const float*)d_in[7];
  const float* b4 = (const float*)d_in[8];
  char* ws = (char*)d_ws;
  short* xt    = (short*)(ws + 0);          // 8,388,608
  short* w123  = (short*)(ws + 8388608);    //   196,608
  short* theta = (short*)(ws + 8585216);    // 4,194,304
  short* phi   = (short*)(ws + 12779520);   // 4,194,304
  short* gT    = (short*)(ws + 16973824);   // 4,194,304
  float* dpart = (float*)(ws + 21168128);   // 2,097,152
  float* dinv  = (float*)(ws + 23265280);   //    65,536
  short* ypart = (short*)(ws + 23330816);   // 16,777,216 (end 40,108,032)
  float* out   = (float*)d_out;
  (void)in_sizes; (void)n_in; (void)out_size; (void)ws_size;

  k_prep<<<dim3(64, 5, 4), dim3(256), 0, stream>>>(x, w1, w2, w3, xt, w123);
  k_proj<<<dim3(32, 3, 4), dim3(256), 0, stream>>>(xt, w123, b1, b2, b3, theta, phi, gT);
  k_denom<<<dim3(32, 4, 4), dim3(256), 0, stream>>>(theta, phi, dpart);
  k_dred<<<dim3(16), dim3(256), 0, stream>>>(dpart, dinv);
  k_attn<<<dim3(32, 4, 4), dim3(256), 0, stream>>>(theta, phi, gT, dinv, ypart);
  k_out<<<dim3(32, 2, 4), dim3(256), 0, stream>>>(ypart, w4, b4, x, out);
}